// Round 6
// baseline (1740.937 us; speedup 1.0000x reference)
//
#include <hip/hip_runtime.h>
#include <hip/hip_bf16.h>

#define BS 8
#define HID 64
#define NV 1024
#define NSTEP 64

// out layout (float32, concatenated flat, element offsets):
//   imps  [8][1][1024][64]  at 0
//   preds [8][1][1024][64]  at 524288
//   reprs [8][64][1024][64] at 1048576
#define IMPS_OFF  0
#define PREDS_OFF 524288
#define REPRS_OFF 1048576

typedef unsigned short u16;
typedef __attribute__((ext_vector_type(8))) short bf8;   // 8 bf16 = one MFMA operand
typedef __attribute__((ext_vector_type(4))) float f4;    // 4 f32 accumulator

__device__ __forceinline__ u16 f2bf(float f){
    __hip_bfloat16 h = __float2bfloat16(f);
    return *reinterpret_cast<u16*>(&h);
}
// 8 packed bf16 (uint4) -> 8 f32
__device__ __forceinline__ void cv8(uint4 u, float* o){
    o[0] = __uint_as_float(u.x << 16); o[1] = __uint_as_float(u.x & 0xffff0000u);
    o[2] = __uint_as_float(u.y << 16); o[3] = __uint_as_float(u.y & 0xffff0000u);
    o[4] = __uint_as_float(u.z << 16); o[5] = __uint_as_float(u.z & 0xffff0000u);
    o[6] = __uint_as_float(u.w << 16); o[7] = __uint_as_float(u.w & 0xffff0000u);
}
__device__ __forceinline__ float sigmoidf_(float v){ return 1.f / (1.f + __expf(-v)); }

// ---------------- convert f32 inputs -> bf16 working copies ----------------
__global__ void conv_k(const float* __restrict__ g, const float* __restrict__ ig,
                       const float* __restrict__ whh, const float* __restrict__ h0,
                       u16* __restrict__ g_b, u16* __restrict__ ig_b,
                       u16* __restrict__ whh_b, u16* __restrict__ hws){
    int gid = blockIdx.x * blockDim.x + threadIdx.x;
    int nt = gridDim.x * blockDim.x;
    for (int i = gid; i < NV*NV; i += nt){ g_b[i] = f2bf(g[i]); ig_b[i] = f2bf(ig[i]); }
    for (int i = gid; i < 192*64; i += nt) whh_b[i] = f2bf(whh[i]);
    for (int i = gid; i < BS*HID*NV; i += nt) hws[i] = f2bf(h0[i & (HID*NV - 1)]);
}

// ---------------- preds[t=0] = W_init . h0 + b_init (f32) ----------------
__global__ void init_k(const float* __restrict__ h0, const float* __restrict__ Wini,
                       const float* __restrict__ bini, float* __restrict__ out){
    int v = blockIdx.x * blockDim.x + threadIdx.x;
    if (v < NV){
        float s = 0.f;
        for (int h = 0; h < HID; ++h) s += h0[h*NV + v] * Wini[h];
        s += bini[0];
        for (int b = 0; b < BS; ++b)
            out[PREDS_OFF + (size_t)b*65536 + (size_t)v*64] = s;
    }
}

// ---------------- one recurrence step (MFMA, barrier-free K-loop) ----------------
// grid: 512 blocks = (blockIdx&7)=batch, (blockIdx>>3)=node-tile (16 nodes)
// 256 threads = 4 waves; wave wv owns h-strip [16wv,16wv+16). ~40 KB LDS -> 2 blocks/CU.
__global__ __launch_bounds__(256) void step_k(
    int t,
    const u16* __restrict__ hin, u16* __restrict__ hout,
    const u16* __restrict__ g_b, const u16* __restrict__ ig_b,
    const u16* __restrict__ whh_b,
    const float* __restrict__ x, const int* __restrict__ mask,
    const float* __restrict__ Wih, const float* __restrict__ bih,
    const float* __restrict__ bhh,
    const float* __restrict__ Wini, const float* __restrict__ bini,
    const float* __restrict__ Wo, const float* __restrict__ bo,
    float* out, float* __restrict__ rtmp, int staged)
{
    __shared__ __align__(16) u16 Gs[16][1032];   // 33 KB graph tile [w][k], stride 516 words
    __shared__ float xh_s[NV];                   // 4 KB
    __shared__ __align__(16) u16 hdb[16][72];    // 2.3 KB h_diff bf16 [w][h]
    __shared__ float r1s[4][17], r2s[4][17];     // head partials
    __shared__ float xg_s[16];

    const int tid  = threadIdx.x;
    const int b    = blockIdx.x & 7;
    const int w0   = (blockIdx.x >> 3) << 4;
    const int lane = tid & 63;
    const int wv   = tid >> 6;       // wave id 0..3
    const int m16  = lane & 15;
    const int quad = lane >> 4;

    // ---- staging: graph tile -> LDS (coalesced), x_hat -> LDS ----
    {
        int row = tid >> 4, seg = tid & 15;
        const u16* gr = g_b + (size_t)(w0 + row)*NV + seg*64;
        u16* ds = &Gs[row][seg*64];
        #pragma unroll
        for (int j = 0; j < 8; ++j)
            *(uint4*)(ds + j*8) = *(const uint4*)(gr + j*8);
    }
    {
        size_t base = (size_t)b*65536 + (size_t)t;
        #pragma unroll
        for (int k = 0; k < 4; ++k){
            int v = tid + k*256;
            size_t idx = base + (size_t)v*64;
            xh_s[v] = mask[idx] ? x[idx] : out[PREDS_OFF + idx];
        }
    }
    __syncthreads();   // B1

    // ---- phase 1: x_g[w] = sum_v x_hat[v]*ig[w][v]; wave wv rows wv*4+quad ----
    {
        int w = wv*4 + quad;
        const u16* igr = ig_b + (size_t)(w0 + w)*NV + m16*64;
        const float* xr = &xh_s[m16*64];
        float acc = 0.f;
        #pragma unroll
        for (int j = 0; j < 8; ++j){
            uint4 u = *(const uint4*)(igr + j*8);
            float gg[8]; cv8(u, gg);
            #pragma unroll
            for (int q2 = 0; q2 < 8; ++q2) acc += gg[q2]*xr[j*8 + q2];
        }
        acc += __shfl_xor(acc, 1); acc += __shfl_xor(acc, 2);
        acc += __shfl_xor(acc, 4); acc += __shfl_xor(acc, 8);
        if (m16 == 0) xg_s[w] = acc;   // visible after B2
    }

    // ---- phase 2: h_diff = h . graph^T, K=1024, NO barriers ----
    // A frag straight from global (L2-warm); B frag from LDS Gs. 2 acc chains.
    const u16* ha = hin + (size_t)b*HID*NV + (size_t)(wv*16 + m16)*NV + quad*8;
    f4 ae = {0.f,0.f,0.f,0.f}, ao = {0.f,0.f,0.f,0.f};
    #pragma unroll 4
    for (int it = 0; it < 32; it += 2){
        bf8 a0 = *(const bf8*)(ha + it*32);
        bf8 a1 = *(const bf8*)(ha + it*32 + 32);
        bf8 b0 = *(const bf8*)&Gs[m16][it*32 + quad*8];
        bf8 b1 = *(const bf8*)&Gs[m16][it*32 + 32 + quad*8];
        ae = __builtin_amdgcn_mfma_f32_16x16x32_bf16(a0, b0, ae, 0, 0, 0);
        ao = __builtin_amdgcn_mfma_f32_16x16x32_bf16(a1, b1, ao, 0, 0, 0);
    }
    f4 hd;
    #pragma unroll
    for (int r = 0; r < 4; ++r) hd[r] = ae[r] + ao[r];
    // lane holds h_diff[h = wv*16+quad*4+r][w = m16]; share bf16 copy for gate GEMM
    {
        ushort4 pk;
        pk.x = f2bf(hd[0]); pk.y = f2bf(hd[1]); pk.z = f2bf(hd[2]); pk.w = f2bf(hd[3]);
        *(ushort4*)&hdb[m16][wv*16 + quad*4] = pk;
    }
    __syncthreads();   // B2

    // ---- phase 3: gates = W_hh . h_diff (K=64); wave wv -> h in [16wv,16wv+16) ----
    bf8 hf0 = *(const bf8*)&hdb[m16][quad*8];
    bf8 hf1 = *(const bf8*)&hdb[m16][32 + quad*8];
    f4 g0 = {0.f,0.f,0.f,0.f}, g1 = {0.f,0.f,0.f,0.f}, g2 = {0.f,0.f,0.f,0.f};
    {
        const u16* wb = whh_b + (size_t)(wv*16 + m16)*64 + quad*8;
        bf8 w00 = *(const bf8*)(wb);
        bf8 w01 = *(const bf8*)(wb + 32);
        bf8 w10 = *(const bf8*)(wb + 64*64);
        bf8 w11 = *(const bf8*)(wb + 64*64 + 32);
        bf8 w20 = *(const bf8*)(wb + 128*64);
        bf8 w21 = *(const bf8*)(wb + 128*64 + 32);
        g0 = __builtin_amdgcn_mfma_f32_16x16x32_bf16(w00, hf0, g0, 0, 0, 0);
        g0 = __builtin_amdgcn_mfma_f32_16x16x32_bf16(w01, hf1, g0, 0, 0, 0);
        g1 = __builtin_amdgcn_mfma_f32_16x16x32_bf16(w10, hf0, g1, 0, 0, 0);
        g1 = __builtin_amdgcn_mfma_f32_16x16x32_bf16(w11, hf1, g1, 0, 0, 0);
        g2 = __builtin_amdgcn_mfma_f32_16x16x32_bf16(w20, hf0, g2, 0, 0, 0);
        g2 = __builtin_amdgcn_mfma_f32_16x16x32_bf16(w21, hf1, g2, 0, 0, 0);
    }

    // ---- phase 4: GRU elementwise + stores + head partials (all in-register) ----
    {
        int wg = w0 + m16;
        float xg = xg_s[m16];
        float p1 = 0.f, p2 = 0.f;
        #pragma unroll
        for (int r = 0; r < 4; ++r){
            int h = wv*16 + quad*4 + r;
            float ir  = xg * Wih[h]       + bih[h];
            float iz  = xg * Wih[64 + h]  + bih[64 + h];
            float inn = xg * Wih[128 + h] + bih[128 + h];
            float rg = sigmoidf_(ir + g0[r] + bhh[h]);
            float zg = sigmoidf_(iz + g1[r] + bhh[64 + h]);
            float ng = tanhf(inn + rg * (g2[r] + bhh[128 + h]));
            float hnew = (1.f - zg) * ng + zg * hd[r];
            hout[(size_t)b*HID*NV + (size_t)h*NV + wg] = f2bf(hnew);
            if (staged) rtmp[(((size_t)t*BS + b)*HID + h)*NV + wg] = hnew;
            else        out[REPRS_OFF + (((size_t)b*HID + h)*NV + wg)*64 + t] = hnew;
            p1 += Wini[h] * hnew;
            p2 += Wo[h]   * hnew;
        }
        // reduce over quads (h-strip of this wave) for fixed w = m16
        p1 += __shfl_down(p1, 32); p1 += __shfl_down(p1, 16);
        p2 += __shfl_down(p2, 32); p2 += __shfl_down(p2, 16);
        if (lane < 16){ r1s[wv][lane] = p1; r2s[wv][lane] = p2; }
    }
    __syncthreads();   // B3

    if (tid < 16){
        int wg = w0 + tid;
        float s1 = r1s[0][tid] + r1s[1][tid] + r1s[2][tid] + r1s[3][tid] + bini[0];
        float s2 = r2s[0][tid] + r2s[1][tid] + r2s[2][tid] + r2s[3][tid] + bo[0];
        size_t base = (size_t)b*65536 + (size_t)wg*64;
        out[IMPS_OFF + base + t] = s2;                 // imps[t]
        if (t < NSTEP - 1)
            out[PREDS_OFF + base + t + 1] = s1;        // preds[t+1]
    }
}

// ---------------- reprs staging [t][b][h][v] -> out [b][h][v][t] ----------------
__global__ void transpose_k(const float* __restrict__ rtmp, float* __restrict__ out){
    __shared__ float tile[64][65];
    int bh = blockIdx.x >> 4;          // 0..511 = b*64 + h
    int b  = bh >> 6, h = bh & 63;
    int v0 = (blockIdx.x & 15) << 6;
    int tid = threadIdx.x;
    int q = tid >> 6, l = tid & 63;
    #pragma unroll 4
    for (int r = 0; r < 16; ++r){
        int tt = r*4 + q;
        tile[tt][l] = rtmp[(((size_t)tt*BS + b)*HID + h)*NV + v0 + l];
    }
    __syncthreads();
    #pragma unroll 4
    for (int r = 0; r < 16; ++r){
        int vv = r*4 + q;
        out[REPRS_OFF + (((size_t)b*HID + h)*NV + v0 + vv)*64 + l] = tile[l][vv];
    }
}

extern "C" void kernel_launch(void* const* d_in, const int* in_sizes, int n_in,
                              void* d_out, int out_size, void* d_ws, size_t ws_size,
                              hipStream_t stream) {
    const float* x     = (const float*)d_in[0];
    const int*   mask  = (const int*)  d_in[1];
    const float* graph = (const float*)d_in[2];
    const float* ind   = (const float*)d_in[3];
    const float* h0    = (const float*)d_in[4];
    const float* Wini  = (const float*)d_in[5];
    const float* bini  = (const float*)d_in[6];
    const float* Wo    = (const float*)d_in[7];
    const float* bo    = (const float*)d_in[8];
    const float* Wih   = (const float*)d_in[9];
    const float* Whh   = (const float*)d_in[10];
    const float* bih   = (const float*)d_in[11];
    const float* bhh   = (const float*)d_in[12];
    float* out = (float*)d_out;

    char* ws = (char*)d_ws;
    u16*   hws   = (u16*)(ws);                         // 2 x 1 MB bf16 h ping-pong
    u16*   g_b   = (u16*)(ws + ((size_t)2<<20));       // 2 MB
    u16*   ig_b  = (u16*)(ws + ((size_t)4<<20));       // 2 MB
    u16*   whh_b = (u16*)(ws + ((size_t)6<<20));       // 24 KB
    float* rtmp  = (float*)(ws + ((size_t)8<<20));     // 128 MB reprs staging
    size_t need_staged = ((size_t)8<<20) + (size_t)NSTEP*BS*HID*NV*4;
    int staged = (ws_size >= need_staged) ? 1 : 0;

    conv_k<<<dim3(2048), dim3(256), 0, stream>>>(graph, ind, Whh, h0,
                                                 g_b, ig_b, whh_b, hws);
    init_k<<<dim3(4), dim3(256), 0, stream>>>(h0, Wini, bini, out);
    for (int t = 0; t < NSTEP; ++t){
        const u16* hin  = hws + (size_t)(t & 1) * (BS*HID*NV);
        u16*       hout = hws + (size_t)((t+1) & 1) * (BS*HID*NV);
        step_k<<<dim3(512), dim3(256), 0, stream>>>(
            t, hin, hout, g_b, ig_b, whh_b, x, mask,
            Wih, bih, bhh, Wini, bini, Wo, bo, out, rtmp, staged);
    }
    if (staged) transpose_k<<<dim3(8192), dim3(256), 0, stream>>>(rtmp, out);
}